// Round 6
// baseline (71.436 us; speedup 1.0000x reference)
//
#include <hip/hip_runtime.h>
#include <hip/hip_bf16.h>

// Problem constants (fixed by setup_inputs)
#define BATCH 4
#define NNODES 4096
#define HID 256
#define NHEADS 8
#define DH 32
#define DEG 16
#define NEDGES (BATCH * NNODES * DEG)   // 262144
#define NROWS (BATCH * NNODES)          // 16384 node-rows

typedef __attribute__((ext_vector_type(8))) short short8;
typedef __attribute__((ext_vector_type(8))) unsigned short ushort8;
typedef __attribute__((ext_vector_type(4))) unsigned short u16x4;  // 'ushort4' collides with HIP types
typedef __attribute__((ext_vector_type(4))) float f32x4;

static __device__ __forceinline__ unsigned short f2bf(float f) {
  __hip_bfloat16 h = __float2bfloat16(f);  // RNE
  return *reinterpret_cast<unsigned short*>(&h);
}
static __device__ __forceinline__ float bf2f(unsigned short u) {
  unsigned int v = ((unsigned int)u) << 16;
  return *reinterpret_cast<float*>(&v);
}

// ---------------------------------------------------------------------------
// Fused QKV projection (prep eliminated). Grid 3072 blocks, strip-major:
// s = bx>>8 (mat = s>>2, cols [(s&3)*64,+64)), chunk = bx&255 (64 rows).
// Per block: (1) transpose+convert its W fp32 strip into fragment-ordered
// LDS sW[kk 8][hi 4][col 64][j 8] = bf16(W[kk*32+hi*8+j][c0+col]);
// (2) load A-frags from fp32 X, convert in-register; (3) 4 nt-tiles of
// swapped-operand MFMA: mfma(Bf, Af) -> lane&15 = X-row, hi*4+reg = 4
// consecutive W-cols -> float4 (Q) / packed bf16x4 (K,V) stores.
// ---------------------------------------------------------------------------
__global__ __launch_bounds__(256, 4) void qkv_mfma_kernel(
    const float* __restrict__ X,
    const float* __restrict__ Wq, const float* __restrict__ Wk,
    const float* __restrict__ Wv,
    const float* __restrict__ bq, const float* __restrict__ bk,
    const float* __restrict__ bv,
    float* __restrict__ Qs, unsigned short* __restrict__ Kb,
    unsigned short* __restrict__ Vb) {
  __shared__ unsigned short sW[16384];  // 32 KB

  const int tid = threadIdx.x;
  const int s = blockIdx.x >> 8;        // 0..11
  const int chunk = blockIdx.x & 255;   // 0..255
  const int mat = s >> 2;               // 0=Q 1=K 2=V
  const int c0 = (s & 3) * 64;
  const float* __restrict__ W = (mat == 0) ? Wq : (mat == 1) ? Wk : Wv;

  // --- Stage W strip: transpose + fp32->bf16 into fragment order. ---
  // iter i: k = i*16 + (tid>>4), 16 lanes cover 64B contiguous per k-row.
  #pragma unroll
  for (int i = 0; i < 16; ++i) {
    const int k = i * 16 + (tid >> 4);
    const int col = (tid & 15) * 4;
    const float4 w4 = *reinterpret_cast<const float4*>(&W[(size_t)k * HID + c0 + col]);
    const int base = (k >> 5) * 2048 + ((k >> 3) & 3) * 512 + (k & 7);
    sW[base + (col + 0) * 8] = f2bf(w4.x);
    sW[base + (col + 1) * 8] = f2bf(w4.y);
    sW[base + (col + 2) * 8] = f2bf(w4.z);
    sW[base + (col + 3) * 8] = f2bf(w4.w);
  }

  const int lane = tid & 63;
  const int wv = tid >> 6;
  const int lm = lane & 15;
  const int hi = lane >> 4;             // 0..3
  const int lk = hi * 8;
  const int row = chunk * 64 + wv * 16 + lm;

  // --- A-fragments from fp32 X, converted in-register. ---
  short8 Af[8];
  #pragma unroll
  for (int kk = 0; kk < 8; ++kk) {
    const float4 a0 = *reinterpret_cast<const float4*>(&X[(size_t)row * 256 + kk * 32 + lk]);
    const float4 a1 = *reinterpret_cast<const float4*>(&X[(size_t)row * 256 + kk * 32 + lk + 4]);
    short8 v;
    v[0] = (short)f2bf(a0.x); v[1] = (short)f2bf(a0.y);
    v[2] = (short)f2bf(a0.z); v[3] = (short)f2bf(a0.w);
    v[4] = (short)f2bf(a1.x); v[5] = (short)f2bf(a1.y);
    v[6] = (short)f2bf(a1.z); v[7] = (short)f2bf(a1.w);
    Af[kk] = v;
  }

  const float* __restrict__ bias = (mat == 0) ? bq : (mat == 1) ? bk : bv;

  __syncthreads();

  #pragma unroll
  for (int nt = 0; nt < 4; ++nt) {
    short8 Bf[8];
    #pragma unroll
    for (int kk = 0; kk < 8; ++kk) {
      Bf[kk] = *reinterpret_cast<const short8*>(
          &sW[kk * 2048 + hi * 512 + (nt * 16 + lm) * 8]);
    }
    f32x4 acc = {0.f, 0.f, 0.f, 0.f};
    #pragma unroll
    for (int kk = 0; kk < 8; ++kk) {
      acc = __builtin_amdgcn_mfma_f32_16x16x32_bf16(Bf[kk], Af[kk], acc, 0, 0, 0);
    }
    const int col0 = c0 + nt * 16 + hi * 4;
    const float4 b4 = *reinterpret_cast<const float4*>(&bias[col0]);
    if (mat == 0) {
      float4 o;
      o.x = acc[0] + b4.x; o.y = acc[1] + b4.y;
      o.z = acc[2] + b4.z; o.w = acc[3] + b4.w;
      *reinterpret_cast<float4*>(&Qs[(size_t)row * 256 + col0]) = o;
    } else {
      u16x4 o;
      o[0] = f2bf(acc[0] + b4.x); o[1] = f2bf(acc[1] + b4.y);
      o[2] = f2bf(acc[2] + b4.z); o[3] = f2bf(acc[3] + b4.w);
      unsigned short* __restrict__ dst = (mat == 1) ? Kb : Vb;
      *reinterpret_cast<u16x4*>(&dst[(size_t)row * 256 + col0]) = o;
    }
  }
}

// ---------------------------------------------------------------------------
// Attention, one-barrier version. One block per segment (16 consecutive
// edges), 256 threads = 4 waves; wave w owns heads {2w, 2w+1}.
// Lane map: lane = j*4 + hh*2 + p  (j = edge 0..15, h = 2*wave+hh, p = half).
// Phase 1: 16-channel dot per lane (Q direct from global, K bf16 gather),
//   shfl_xor(1) combines p; softmax over j via shfl_xor(4,8,16,32) in-wave.
// One s_w write + ONE barrier; phase 3: tid=channel, 16 V-gather FMAs
//   (edge ids re-read as block-uniform scalar loads).
// XCD swizzle: each XCD works one batch -> K/V L2 locality.
// ---------------------------------------------------------------------------
__global__ __launch_bounds__(256) void attn_kernel(
    const float* __restrict__ Q, const unsigned short* __restrict__ K,
    const unsigned short* __restrict__ V, const int* __restrict__ edges,
    float* __restrict__ out) {
  __shared__ float s_w[DEG * NHEADS];   // [j][h], 512 B

  const int bx = blockIdx.x;
  const int xcd = bx & 7;
  const int g = (xcd >> 1) * NNODES + (((bx >> 3) << 1) | (xcd & 1));
  const int e0 = g * DEG;
  const int tid = threadIdx.x;

  const int b = edges[e0];                            // block-uniform
  const int qrow = b * NNODES + edges[NEDGES + e0];   // block-uniform

  // ---- Phase 1 + in-wave softmax ----
  const int lane = tid & 63;
  const int wv = tid >> 6;
  const int j = lane >> 2;
  const int hh = (lane >> 1) & 1;
  const int p = lane & 1;
  const int h = wv * 2 + hh;
  const int ch0 = h * 32 + p * 16;

  const int nsrc = b * NNODES + edges[2 * NEDGES + e0 + j];  // 16 distinct, coalesced

  const float* __restrict__ qp = &Q[(size_t)qrow * HID + ch0];
  const float4 q0 = *reinterpret_cast<const float4*>(qp);
  const float4 q1 = *reinterpret_cast<const float4*>(qp + 4);
  const float4 q2 = *reinterpret_cast<const float4*>(qp + 8);
  const float4 q3 = *reinterpret_cast<const float4*>(qp + 12);
  const unsigned short* __restrict__ kp = &K[(size_t)nsrc * HID + ch0];
  const ushort8 k0 = *reinterpret_cast<const ushort8*>(kp);
  const ushort8 k1 = *reinterpret_cast<const ushort8*>(kp + 8);

  float partial;
  partial  = q0.x * bf2f(k0[0]); partial = fmaf(q0.y, bf2f(k0[1]), partial);
  partial = fmaf(q0.z, bf2f(k0[2]), partial); partial = fmaf(q0.w, bf2f(k0[3]), partial);
  partial = fmaf(q1.x, bf2f(k0[4]), partial); partial = fmaf(q1.y, bf2f(k0[5]), partial);
  partial = fmaf(q1.z, bf2f(k0[6]), partial); partial = fmaf(q1.w, bf2f(k0[7]), partial);
  partial = fmaf(q2.x, bf2f(k1[0]), partial); partial = fmaf(q2.y, bf2f(k1[1]), partial);
  partial = fmaf(q2.z, bf2f(k1[2]), partial); partial = fmaf(q2.w, bf2f(k1[3]), partial);
  partial = fmaf(q3.x, bf2f(k1[4]), partial); partial = fmaf(q3.y, bf2f(k1[5]), partial);
  partial = fmaf(q3.z, bf2f(k1[6]), partial); partial = fmaf(q3.w, bf2f(k1[7]), partial);

  partial += __shfl_xor(partial, 1);                 // combine p-halves
  const float sc = partial * 0.17677669529663687f;   // 1/sqrt(DH)

  float mx = sc;                                     // reduce over j (lane bits 2..5)
  mx = fmaxf(mx, __shfl_xor(mx, 4));
  mx = fmaxf(mx, __shfl_xor(mx, 8));
  mx = fmaxf(mx, __shfl_xor(mx, 16));
  mx = fmaxf(mx, __shfl_xor(mx, 32));
  const float e = __expf(sc - mx);
  float sum = e;
  sum += __shfl_xor(sum, 4);
  sum += __shfl_xor(sum, 8);
  sum += __shfl_xor(sum, 16);
  sum += __shfl_xor(sum, 32);

  if (p == 0) s_w[j * NHEADS + h] = e / sum;
  __syncthreads();

  // ---- Phase 3: weighted V gather-sum (tid = channel) ----
  const int h3 = tid >> 5;
  float acc = 0.0f;
  #pragma unroll
  for (int jj = 0; jj < DEG; ++jj) {
    const int n = b * NNODES + edges[2 * NEDGES + e0 + jj];  // uniform scalar loads
    acc = fmaf(s_w[jj * NHEADS + h3], bf2f(V[(size_t)n * HID + tid]), acc);
  }
  out[(size_t)qrow * HID + tid] = acc;
}

// ---------------------------------------------------------------------------
extern "C" void kernel_launch(void* const* d_in, const int* in_sizes, int n_in,
                              void* d_out, int out_size, void* d_ws, size_t ws_size,
                              hipStream_t stream) {
  const float* X     = (const float*)d_in[0];
  const int*   edges = (const int*)d_in[1];
  const float* Wq    = (const float*)d_in[2];
  const float* bq    = (const float*)d_in[3];
  const float* Wk    = (const float*)d_in[4];
  const float* bk    = (const float*)d_in[5];
  const float* Wv    = (const float*)d_in[6];
  const float* bv    = (const float*)d_in[7];
  float* out = (float*)d_out;

  // Workspace: Qs fp32 16MiB | Kb bf16 8MiB | Vb bf16 8MiB  (32 MiB total)
  char* w = (char*)d_ws;
  float*          Qs = (float*)w;                 w += (size_t)NROWS * HID * 4;
  unsigned short* Kb = (unsigned short*)w;        w += (size_t)NROWS * HID * 2;
  unsigned short* Vb = (unsigned short*)w;

  qkv_mfma_kernel<<<3072, 256, 0, stream>>>(X, Wq, Wk, Wv, bq, bk, bv, Qs, Kb, Vb);
  attn_kernel<<<NROWS, 256, 0, stream>>>(Qs, Kb, Vb, edges, out);
}

// Round 7
// 70.178 us; speedup vs baseline: 1.0179x; 1.0179x over previous
//
#include <hip/hip_runtime.h>
#include <hip/hip_bf16.h>

// Problem constants (fixed by setup_inputs)
#define BATCH 4
#define NNODES 4096
#define HID 256
#define NHEADS 8
#define DH 32
#define DEG 16
#define NEDGES (BATCH * NNODES * DEG)   // 262144
#define NROWS (BATCH * NNODES)          // 16384 node-rows

typedef __attribute__((ext_vector_type(8))) short short8;
typedef __attribute__((ext_vector_type(8))) unsigned short ushort8;
typedef __attribute__((ext_vector_type(4))) unsigned short u16x4;  // 'ushort4' collides with HIP types
typedef __attribute__((ext_vector_type(4))) float f32x4;

static __device__ __forceinline__ unsigned short f2bf(float f) {
  __hip_bfloat16 h = __float2bfloat16(f);  // RNE
  return *reinterpret_cast<unsigned short*>(&h);
}
static __device__ __forceinline__ float bf2f(unsigned short u) {
  unsigned int v = ((unsigned int)u) << 16;
  return *reinterpret_cast<float*>(&v);
}

// ---------------------------------------------------------------------------
// Fused QKV projection. 3072 blocks = 8 XCDs x (12 strips x 32 chunk-groups).
// XCD-local chunk-major order: per-XCD local index l = bx>>3,
//   strip s = l%12 (mat = s>>2, cols [(s&3)*64,+64)),
//   chunk  = (l/12)*8 + xcd  (64 rows).
// The 12 blocks sharing an X chunk run consecutively on the SAME XCD ->
// X chunk lives in that XCD's L2 across all 12 uses.
//
// W staging (conflict-free): thread owns output elem = kk*256 + hi*64 + col
// (8 iters), gathers 8 k-values with lane-coalesced reads (256B/wave per j),
// converts, writes ONE ds_write_b128 at consecutive 16B/lane -> 0 conflicts.
// LDS layout sW[kk 8][hi 4][col 64][j 8] = bf16(W[kk*32+hi*8+j][c0+col]).
//
// MFMA operands swapped: mfma(Bf, Af) -> lane&15 = X-row, hi*4+reg = 4
// consecutive W-cols -> float4 (Q) / packed bf16x4 (K,V) stores.
// ---------------------------------------------------------------------------
__global__ __launch_bounds__(256, 4) void qkv_mfma_kernel(
    const float* __restrict__ X,
    const float* __restrict__ Wq, const float* __restrict__ Wk,
    const float* __restrict__ Wv,
    const float* __restrict__ bq, const float* __restrict__ bk,
    const float* __restrict__ bv,
    float* __restrict__ Qs, unsigned short* __restrict__ Kb,
    unsigned short* __restrict__ Vb) {
  __shared__ unsigned short sW[16384];  // 32 KB

  const int tid = threadIdx.x;
  const int xcd = blockIdx.x & 7;
  const int l = blockIdx.x >> 3;        // 0..383
  const int s = l % 12;
  const int chunk = (l / 12) * 8 + xcd; // 0..255, XCD-local
  const int mat = s >> 2;               // 0=Q 1=K 2=V
  const int c0 = (s & 3) * 64;
  const float* __restrict__ W = (mat == 0) ? Wq : (mat == 1) ? Wk : Wv;

  // --- Stage W strip: gather-transpose, conflict-free b128 writes. ---
  #pragma unroll
  for (int i = 0; i < 8; ++i) {          // i = kk
    const int hi_s = tid >> 6;
    const int col = tid & 63;
    const int k0 = i * 32 + hi_s * 8;
    ushort8 o;
    #pragma unroll
    for (int j = 0; j < 8; ++j) {
      o[j] = f2bf(W[(size_t)(k0 + j) * HID + c0 + col]);
    }
    *reinterpret_cast<ushort8*>(&sW[(i * 256 + tid) * 8]) = o;
  }

  const int lane = tid & 63;
  const int wv = tid >> 6;
  const int lm = lane & 15;
  const int hi = lane >> 4;             // 0..3
  const int lk = hi * 8;
  const int row = chunk * 64 + wv * 16 + lm;

  // --- A-fragments from fp32 X, converted in-register. ---
  short8 Af[8];
  #pragma unroll
  for (int kk = 0; kk < 8; ++kk) {
    const float4 a0 = *reinterpret_cast<const float4*>(&X[(size_t)row * 256 + kk * 32 + lk]);
    const float4 a1 = *reinterpret_cast<const float4*>(&X[(size_t)row * 256 + kk * 32 + lk + 4]);
    short8 v;
    v[0] = (short)f2bf(a0.x); v[1] = (short)f2bf(a0.y);
    v[2] = (short)f2bf(a0.z); v[3] = (short)f2bf(a0.w);
    v[4] = (short)f2bf(a1.x); v[5] = (short)f2bf(a1.y);
    v[6] = (short)f2bf(a1.z); v[7] = (short)f2bf(a1.w);
    Af[kk] = v;
  }

  const float* __restrict__ bias = (mat == 0) ? bq : (mat == 1) ? bk : bv;

  __syncthreads();

  #pragma unroll
  for (int nt = 0; nt < 4; ++nt) {
    short8 Bf[8];
    #pragma unroll
    for (int kk = 0; kk < 8; ++kk) {
      Bf[kk] = *reinterpret_cast<const short8*>(
          &sW[kk * 2048 + hi * 512 + (nt * 16 + lm) * 8]);
    }
    f32x4 acc = {0.f, 0.f, 0.f, 0.f};
    #pragma unroll
    for (int kk = 0; kk < 8; ++kk) {
      acc = __builtin_amdgcn_mfma_f32_16x16x32_bf16(Bf[kk], Af[kk], acc, 0, 0, 0);
    }
    const int col0 = c0 + nt * 16 + hi * 4;
    const float4 b4 = *reinterpret_cast<const float4*>(&bias[col0]);
    if (mat == 0) {
      float4 o;
      o.x = acc[0] + b4.x; o.y = acc[1] + b4.y;
      o.z = acc[2] + b4.z; o.w = acc[3] + b4.w;
      *reinterpret_cast<float4*>(&Qs[(size_t)row * 256 + col0]) = o;
    } else {
      u16x4 o;
      o[0] = f2bf(acc[0] + b4.x); o[1] = f2bf(acc[1] + b4.y);
      o[2] = f2bf(acc[2] + b4.z); o[3] = f2bf(acc[3] + b4.w);
      unsigned short* __restrict__ dst = (mat == 1) ? Kb : Vb;
      *reinterpret_cast<u16x4*>(&dst[(size_t)row * 256 + col0]) = o;
    }
  }
}

// ---------------------------------------------------------------------------
// Attention, one-barrier version (unchanged from R6). One block per segment,
// 256 threads = 4 waves; wave w owns heads {2w, 2w+1}.
// Lane map: lane = j*4 + hh*2 + p. In-wave softmax over j (lane bits 2..5).
// One s_w write + ONE barrier; phase 3: tid=channel, 16 V-gather FMAs.
// XCD swizzle: each XCD works one batch -> K/V L2 locality.
// ---------------------------------------------------------------------------
__global__ __launch_bounds__(256) void attn_kernel(
    const float* __restrict__ Q, const unsigned short* __restrict__ K,
    const unsigned short* __restrict__ V, const int* __restrict__ edges,
    float* __restrict__ out) {
  __shared__ float s_w[DEG * NHEADS];   // [j][h], 512 B

  const int bx = blockIdx.x;
  const int xcd = bx & 7;
  const int g = (xcd >> 1) * NNODES + (((bx >> 3) << 1) | (xcd & 1));
  const int e0 = g * DEG;
  const int tid = threadIdx.x;

  const int b = edges[e0];                            // block-uniform
  const int qrow = b * NNODES + edges[NEDGES + e0];   // block-uniform

  // ---- Phase 1 + in-wave softmax ----
  const int lane = tid & 63;
  const int wv = tid >> 6;
  const int j = lane >> 2;
  const int hh = (lane >> 1) & 1;
  const int p = lane & 1;
  const int h = wv * 2 + hh;
  const int ch0 = h * 32 + p * 16;

  const int nsrc = b * NNODES + edges[2 * NEDGES + e0 + j];  // 16 distinct, coalesced

  const float* __restrict__ qp = &Q[(size_t)qrow * HID + ch0];
  const float4 q0 = *reinterpret_cast<const float4*>(qp);
  const float4 q1 = *reinterpret_cast<const float4*>(qp + 4);
  const float4 q2 = *reinterpret_cast<const float4*>(qp + 8);
  const float4 q3 = *reinterpret_cast<const float4*>(qp + 12);
  const unsigned short* __restrict__ kp = &K[(size_t)nsrc * HID + ch0];
  const ushort8 k0 = *reinterpret_cast<const ushort8*>(kp);
  const ushort8 k1 = *reinterpret_cast<const ushort8*>(kp + 8);

  float partial;
  partial  = q0.x * bf2f(k0[0]); partial = fmaf(q0.y, bf2f(k0[1]), partial);
  partial = fmaf(q0.z, bf2f(k0[2]), partial); partial = fmaf(q0.w, bf2f(k0[3]), partial);
  partial = fmaf(q1.x, bf2f(k0[4]), partial); partial = fmaf(q1.y, bf2f(k0[5]), partial);
  partial = fmaf(q1.z, bf2f(k0[6]), partial); partial = fmaf(q1.w, bf2f(k0[7]), partial);
  partial = fmaf(q2.x, bf2f(k1[0]), partial); partial = fmaf(q2.y, bf2f(k1[1]), partial);
  partial = fmaf(q2.z, bf2f(k1[2]), partial); partial = fmaf(q2.w, bf2f(k1[3]), partial);
  partial = fmaf(q3.x, bf2f(k1[4]), partial); partial = fmaf(q3.y, bf2f(k1[5]), partial);
  partial = fmaf(q3.z, bf2f(k1[6]), partial); partial = fmaf(q3.w, bf2f(k1[7]), partial);

  partial += __shfl_xor(partial, 1);                 // combine p-halves
  const float sc = partial * 0.17677669529663687f;   // 1/sqrt(DH)

  float mx = sc;                                     // reduce over j (lane bits 2..5)
  mx = fmaxf(mx, __shfl_xor(mx, 4));
  mx = fmaxf(mx, __shfl_xor(mx, 8));
  mx = fmaxf(mx, __shfl_xor(mx, 16));
  mx = fmaxf(mx, __shfl_xor(mx, 32));
  const float e = __expf(sc - mx);
  float sum = e;
  sum += __shfl_xor(sum, 4);
  sum += __shfl_xor(sum, 8);
  sum += __shfl_xor(sum, 16);
  sum += __shfl_xor(sum, 32);

  if (p == 0) s_w[j * NHEADS + h] = e / sum;
  __syncthreads();

  // ---- Phase 3: weighted V gather-sum (tid = channel) ----
  const int h3 = tid >> 5;
  float acc = 0.0f;
  #pragma unroll
  for (int jj = 0; jj < DEG; ++jj) {
    const int n = b * NNODES + edges[2 * NEDGES + e0 + jj];  // uniform scalar loads
    acc = fmaf(s_w[jj * NHEADS + h3], bf2f(V[(size_t)n * HID + tid]), acc);
  }
  out[(size_t)qrow * HID + tid] = acc;
}

// ---------------------------------------------------------------------------
extern "C" void kernel_launch(void* const* d_in, const int* in_sizes, int n_in,
                              void* d_out, int out_size, void* d_ws, size_t ws_size,
                              hipStream_t stream) {
  const float* X     = (const float*)d_in[0];
  const int*   edges = (const int*)d_in[1];
  const float* Wq    = (const float*)d_in[2];
  const float* bq    = (const float*)d_in[3];
  const float* Wk    = (const float*)d_in[4];
  const float* bk    = (const float*)d_in[5];
  const float* Wv    = (const float*)d_in[6];
  const float* bv    = (const float*)d_in[7];
  float* out = (float*)d_out;

  // Workspace: Qs fp32 16MiB | Kb bf16 8MiB | Vb bf16 8MiB  (32 MiB total)
  char* w = (char*)d_ws;
  float*          Qs = (float*)w;                 w += (size_t)NROWS * HID * 4;
  unsigned short* Kb = (unsigned short*)w;        w += (size_t)NROWS * HID * 2;
  unsigned short* Vb = (unsigned short*)w;

  qkv_mfma_kernel<<<3072, 256, 0, stream>>>(X, Wq, Wk, Wv, bq, bk, bv, Qs, Kb, Vb);
  attn_kernel<<<NROWS, 256, 0, stream>>>(Qs, Kb, Vb, edges, out);
}

// Round 8
// 63.379 us; speedup vs baseline: 1.1271x; 1.1073x over previous
//
#include <hip/hip_runtime.h>
#include <hip/hip_bf16.h>

// Problem constants (fixed by setup_inputs)
#define BATCH 4
#define NNODES 4096
#define HID 256
#define NHEADS 8
#define DH 32
#define DEG 16
#define NEDGES (BATCH * NNODES * DEG)   // 262144
#define NROWS (BATCH * NNODES)          // 16384 node-rows

typedef __attribute__((ext_vector_type(8))) short short8;
typedef __attribute__((ext_vector_type(8))) unsigned short ushort8;
typedef __attribute__((ext_vector_type(4))) unsigned short u16x4;  // 'ushort4' collides with HIP types
typedef __attribute__((ext_vector_type(4))) float f32x4;

static __device__ __forceinline__ unsigned short f2bf(float f) {
  __hip_bfloat16 h = __float2bfloat16(f);  // RNE
  return *reinterpret_cast<unsigned short*>(&h);
}
static __device__ __forceinline__ float bf2f(unsigned short u) {
  unsigned int v = ((unsigned int)u) << 16;
  return *reinterpret_cast<float*>(&v);
}

// ---------------------------------------------------------------------------
// W prep (one-time, 96 blocks): Wt fragment-ordered bf16,
//   Wt[(mat*4+strip)*16384 + kk*2048 + hi*512 + col*8 + j]
//     = bf16( W_mat[kk*32 + hi*8 + j][strip*64 + col] )
// Exactly the order qkv_mfma's ds_read_b128 consumes -> the in-kernel W
// stage is a LINEAR copy (no per-block transpose redundancy — R7's cost).
// ---------------------------------------------------------------------------
__global__ __launch_bounds__(256) void w_prep_kernel(
    const float* __restrict__ Wq, const float* __restrict__ Wk,
    const float* __restrict__ Wv, unsigned short* __restrict__ Wt) {
  const int o = blockIdx.x * 2048 + threadIdx.x * 8;  // [0, 196608)
  const int mat   = o >> 16;
  const int w     = o & 65535;
  const int strip = w >> 14;
  const int r     = w & 16383;
  const int kk    = r >> 11;
  const int hi    = (r >> 9) & 3;
  const int col   = (r >> 3) & 63;
  const int k0    = kk * 32 + hi * 8;
  const int c     = strip * 64 + col;
  const float* __restrict__ W = (mat == 0) ? Wq : (mat == 1) ? Wk : Wv;
  ushort8 ovec;
  #pragma unroll
  for (int j = 0; j < 8; ++j) {
    ovec[j] = f2bf(W[(size_t)(k0 + j) * HID + c]);
  }
  *reinterpret_cast<ushort8*>(&Wt[o]) = ovec;
}

// ---------------------------------------------------------------------------
// QKV projection with A-reuse. Grid 1024 = 8 XCDs x 128 locals.
//   l = bx>>3: cs = l&3 (cols [cs*64,+64)), chunk = (l>>2)*8 + xcd (64 rows).
// The 4 cs-blocks of one chunk are consecutive on the SAME XCD -> X rows L2-hot.
// Per block: load A-frags ONCE (fp32 X -> in-register bf16), then loop
// mat=0..2 { linear-stage Wt strip (32KB LDS), sync, 4 nt-tiles x 8 MFMA,
// store, sync }. MFMA operands swapped: mfma(Bf, Af) -> lane&15 = X-row,
// hi*4+reg = 4 consecutive W-cols -> float4 (Q) / packed bf16x4 (K,V) stores.
// ---------------------------------------------------------------------------
__global__ __launch_bounds__(256, 4) void qkv_mfma_kernel(
    const float* __restrict__ X, const unsigned short* __restrict__ Wt,
    const float* __restrict__ bq, const float* __restrict__ bk,
    const float* __restrict__ bv,
    float* __restrict__ Qs, unsigned short* __restrict__ Kb,
    unsigned short* __restrict__ Vb) {
  __shared__ unsigned short sW[16384];  // 32 KB

  const int tid = threadIdx.x;
  const int xcd = blockIdx.x & 7;
  const int l = blockIdx.x >> 3;        // 0..127
  const int cs = l & 3;                 // col-strip
  const int chunk = (l >> 2) * 8 + xcd; // 0..255, XCD-local
  const int c0 = cs * 64;

  const int lane = tid & 63;
  const int wv = tid >> 6;
  const int lm = lane & 15;
  const int hi = lane >> 4;             // 0..3
  const int lk = hi * 8;
  const int row = chunk * 64 + wv * 16 + lm;

  // --- A-fragments from fp32 X, converted in-register (loaded ONCE). ---
  short8 Af[8];
  #pragma unroll
  for (int kk = 0; kk < 8; ++kk) {
    const float4 a0 = *reinterpret_cast<const float4*>(&X[(size_t)row * 256 + kk * 32 + lk]);
    const float4 a1 = *reinterpret_cast<const float4*>(&X[(size_t)row * 256 + kk * 32 + lk + 4]);
    short8 v;
    v[0] = (short)f2bf(a0.x); v[1] = (short)f2bf(a0.y);
    v[2] = (short)f2bf(a0.z); v[3] = (short)f2bf(a0.w);
    v[4] = (short)f2bf(a1.x); v[5] = (short)f2bf(a1.y);
    v[6] = (short)f2bf(a1.z); v[7] = (short)f2bf(a1.w);
    Af[kk] = v;
  }

  #pragma unroll
  for (int m = 0; m < 3; ++m) {
    // --- Stage W strip: linear copy of pre-permuted bf16 (conflict-free). ---
    const unsigned short* __restrict__ Wsrc = Wt + (size_t)(m * 4 + cs) * 16384;
    #pragma unroll
    for (int i = 0; i < 8; ++i) {
      const int e = i * 2048 + tid * 8;
      *reinterpret_cast<ushort8*>(&sW[e]) =
          *reinterpret_cast<const ushort8*>(&Wsrc[e]);
    }
    __syncthreads();

    const float* __restrict__ bias = (m == 0) ? bq : (m == 1) ? bk : bv;

    #pragma unroll
    for (int nt = 0; nt < 4; ++nt) {
      short8 Bf[8];
      #pragma unroll
      for (int kk = 0; kk < 8; ++kk) {
        Bf[kk] = *reinterpret_cast<const short8*>(
            &sW[kk * 2048 + hi * 512 + (nt * 16 + lm) * 8]);
      }
      f32x4 acc = {0.f, 0.f, 0.f, 0.f};
      #pragma unroll
      for (int kk = 0; kk < 8; ++kk) {
        acc = __builtin_amdgcn_mfma_f32_16x16x32_bf16(Bf[kk], Af[kk], acc, 0, 0, 0);
      }
      const int col0 = c0 + nt * 16 + hi * 4;
      const float4 b4 = *reinterpret_cast<const float4*>(&bias[col0]);
      if (m == 0) {
        float4 o;
        o.x = acc[0] + b4.x; o.y = acc[1] + b4.y;
        o.z = acc[2] + b4.z; o.w = acc[3] + b4.w;
        *reinterpret_cast<float4*>(&Qs[(size_t)row * 256 + col0]) = o;
      } else {
        u16x4 o;
        o[0] = f2bf(acc[0] + b4.x); o[1] = f2bf(acc[1] + b4.y);
        o[2] = f2bf(acc[2] + b4.z); o[3] = f2bf(acc[3] + b4.w);
        unsigned short* __restrict__ dst = (m == 1) ? Kb : Vb;
        *reinterpret_cast<u16x4*>(&dst[(size_t)row * 256 + col0]) = o;
      }
    }
    __syncthreads();  // sW reused by next mat
  }
}

// ---------------------------------------------------------------------------
// Attention, one-barrier version (unchanged from R6/R7). One block per
// segment, 256 threads = 4 waves; wave w owns heads {2w, 2w+1}.
// Lane map: lane = j*4 + hh*2 + p. In-wave softmax over j (lane bits 2..5).
// One s_w write + ONE barrier; phase 3: tid=channel, 16 V-gather FMAs.
// XCD swizzle: each XCD works one batch -> K/V L2 locality.
// ---------------------------------------------------------------------------
__global__ __launch_bounds__(256) void attn_kernel(
    const float* __restrict__ Q, const unsigned short* __restrict__ K,
    const unsigned short* __restrict__ V, const int* __restrict__ edges,
    float* __restrict__ out) {
  __shared__ float s_w[DEG * NHEADS];   // [j][h], 512 B

  const int bx = blockIdx.x;
  const int xcd = bx & 7;
  const int g = (xcd >> 1) * NNODES + (((bx >> 3) << 1) | (xcd & 1));
  const int e0 = g * DEG;
  const int tid = threadIdx.x;

  const int b = edges[e0];                            // block-uniform
  const int qrow = b * NNODES + edges[NEDGES + e0];   // block-uniform

  // ---- Phase 1 + in-wave softmax ----
  const int lane = tid & 63;
  const int wv = tid >> 6;
  const int j = lane >> 2;
  const int hh = (lane >> 1) & 1;
  const int p = lane & 1;
  const int h = wv * 2 + hh;
  const int ch0 = h * 32 + p * 16;

  const int nsrc = b * NNODES + edges[2 * NEDGES + e0 + j];  // 16 distinct, coalesced

  const float* __restrict__ qp = &Q[(size_t)qrow * HID + ch0];
  const float4 q0 = *reinterpret_cast<const float4*>(qp);
  const float4 q1 = *reinterpret_cast<const float4*>(qp + 4);
  const float4 q2 = *reinterpret_cast<const float4*>(qp + 8);
  const float4 q3 = *reinterpret_cast<const float4*>(qp + 12);
  const unsigned short* __restrict__ kp = &K[(size_t)nsrc * HID + ch0];
  const ushort8 k0 = *reinterpret_cast<const ushort8*>(kp);
  const ushort8 k1 = *reinterpret_cast<const ushort8*>(kp + 8);

  float partial;
  partial  = q0.x * bf2f(k0[0]); partial = fmaf(q0.y, bf2f(k0[1]), partial);
  partial = fmaf(q0.z, bf2f(k0[2]), partial); partial = fmaf(q0.w, bf2f(k0[3]), partial);
  partial = fmaf(q1.x, bf2f(k0[4]), partial); partial = fmaf(q1.y, bf2f(k0[5]), partial);
  partial = fmaf(q1.z, bf2f(k0[6]), partial); partial = fmaf(q1.w, bf2f(k0[7]), partial);
  partial = fmaf(q2.x, bf2f(k1[0]), partial); partial = fmaf(q2.y, bf2f(k1[1]), partial);
  partial = fmaf(q2.z, bf2f(k1[2]), partial); partial = fmaf(q2.w, bf2f(k1[3]), partial);
  partial = fmaf(q3.x, bf2f(k1[4]), partial); partial = fmaf(q3.y, bf2f(k1[5]), partial);
  partial = fmaf(q3.z, bf2f(k1[6]), partial); partial = fmaf(q3.w, bf2f(k1[7]), partial);

  partial += __shfl_xor(partial, 1);                 // combine p-halves
  const float sc = partial * 0.17677669529663687f;   // 1/sqrt(DH)

  float mx = sc;                                     // reduce over j (lane bits 2..5)
  mx = fmaxf(mx, __shfl_xor(mx, 4));
  mx = fmaxf(mx, __shfl_xor(mx, 8));
  mx = fmaxf(mx, __shfl_xor(mx, 16));
  mx = fmaxf(mx, __shfl_xor(mx, 32));
  const float e = __expf(sc - mx);
  float sum = e;
  sum += __shfl_xor(sum, 4);
  sum += __shfl_xor(sum, 8);
  sum += __shfl_xor(sum, 16);
  sum += __shfl_xor(sum, 32);

  if (p == 0) s_w[j * NHEADS + h] = e / sum;
  __syncthreads();

  // ---- Phase 3: weighted V gather-sum (tid = channel) ----
  const int h3 = tid >> 5;
  float acc = 0.0f;
  #pragma unroll
  for (int jj = 0; jj < DEG; ++jj) {
    const int n = b * NNODES + edges[2 * NEDGES + e0 + jj];  // uniform scalar loads
    acc = fmaf(s_w[jj * NHEADS + h3], bf2f(V[(size_t)n * HID + tid]), acc);
  }
  out[(size_t)qrow * HID + tid] = acc;
}

// ---------------------------------------------------------------------------
extern "C" void kernel_launch(void* const* d_in, const int* in_sizes, int n_in,
                              void* d_out, int out_size, void* d_ws, size_t ws_size,
                              hipStream_t stream) {
  const float* X     = (const float*)d_in[0];
  const int*   edges = (const int*)d_in[1];
  const float* Wq    = (const float*)d_in[2];
  const float* bq    = (const float*)d_in[3];
  const float* Wk    = (const float*)d_in[4];
  const float* bk    = (const float*)d_in[5];
  const float* Wv    = (const float*)d_in[6];
  const float* bv    = (const float*)d_in[7];
  float* out = (float*)d_out;

  // Workspace: Qs fp32 16MiB | Kb bf16 8MiB | Vb bf16 8MiB | Wt bf16 384KiB
  char* w = (char*)d_ws;
  float*          Qs = (float*)w;                 w += (size_t)NROWS * HID * 4;
  unsigned short* Kb = (unsigned short*)w;        w += (size_t)NROWS * HID * 2;
  unsigned short* Vb = (unsigned short*)w;        w += (size_t)NROWS * HID * 2;
  unsigned short* Wt = (unsigned short*)w;

  w_prep_kernel<<<96, 256, 0, stream>>>(Wq, Wk, Wv, Wt);
  qkv_mfma_kernel<<<1024, 256, 0, stream>>>(X, Wt, bq, bk, bv, Qs, Kb, Vb);
  attn_kernel<<<NROWS, 256, 0, stream>>>(Qs, Kb, Vb, edges, out);
}